// Round 3
// baseline (30417.465 us; speedup 1.0000x reference)
//
#include <hip/hip_runtime.h>

#define T_STEPS 8192
#define HID 256
#define NBLK 128      // dispatched; 16 co-located on one elected XCD participate
#define THREADS 256   // 4 waves
#define SPIN_T0  4096 // t==0 budget: covers inter-block startup skew (~0.6 ms)
#define SPIN_RUN 64   // t>0 budget: ~9 us, then sticky fallback to agent path

#define MAGIC_READY 0x13579BDFu
#define EMPTY_XCD   0xFFFFFFFFu
#define DONE_MAGIC  0x600DD00Eu

// 2/(1+e^-2x)-1 is inf-safe at both ends
__device__ __forceinline__ float tanh_fast(float x) { return 2.0f / (1.0f + __expf(-2.0f * x)) - 1.0f; }

// Plain 8B store: write-through L1 -> lands in the XCD-local L2 (the coherence
// point the consumer's TCC atomics read). Single-transaction, never tears.
__device__ __forceinline__ void st_u64(unsigned long long* p, unsigned long long v) {
    asm volatile("global_store_dwordx2 %0, %1, off" :: "v"(p), "v"(v) : "memory");
}
// Consumer poll: 4x 8B atomic add-0 with return-old (sc0). Atomics execute AT THE
// TCC -> by construction they bypass L1 and read the current L2 line. This is the
// only read flavor that cannot see a stale L1 copy and does not bypass L2 to the
// IF (the sc1 mistake of R2).
__device__ __forceinline__ void at4_issue(unsigned long long* p,
                                          unsigned long long& a, unsigned long long& b,
                                          unsigned long long& c, unsigned long long& d) {
    unsigned long long z = 0ull;
    asm volatile(
        "global_atomic_add_x2 %0, %4, %5, off sc0\n\t"
        "global_atomic_add_x2 %1, %4, %5, off offset:8 sc0\n\t"
        "global_atomic_add_x2 %2, %4, %5, off offset:16 sc0\n\t"
        "global_atomic_add_x2 %3, %4, %5, off offset:24 sc0"
        : "=&v"(a), "=&v"(b), "=&v"(c), "=&v"(d)
        : "v"(p), "v"(z) : "memory");
}
// Wait with an exact outstanding-count, then dataflow-bind the asm-produced
// values (rule-18: "memory" alone doesn't order register reads of asm outputs).
__device__ __forceinline__ void vm_wait1_bind(unsigned long long& a, unsigned long long& b,
                                              unsigned long long& c, unsigned long long& d) {
    asm volatile("s_waitcnt vmcnt(1)" ::: "memory");   // allow the deferred hbA store to fly
    __builtin_amdgcn_sched_barrier(0);
    asm volatile("" : "+v"(a), "+v"(b), "+v"(c), "+v"(d));
}
__device__ __forceinline__ void vm_wait0_bind(unsigned long long& a, unsigned long long& b,
                                              unsigned long long& c, unsigned long long& d) {
    asm volatile("s_waitcnt vmcnt(0)" ::: "memory");
    __builtin_amdgcn_sched_barrier(0);
    asm volatile("" : "+v"(a), "+v"(b), "+v"(c), "+v"(d));
}

__global__ __launch_bounds__(THREADS, 1)
void lstm_scan(const int* __restrict__ tokens,
               const float* __restrict__ emb,    // [V,256] fp32
               const float* __restrict__ Wih,    // [1024,256] fp32
               const float* __restrict__ Whh,    // [1024,256] fp32
               const float* __restrict__ bih,    // [1024]
               const float* __restrict__ bhh,    // [1024]
               float* __restrict__ out,          // [T*256 + 256 + 256] fp32
               unsigned long long* __restrict__ hbL,   // ws+0:    [2][256] L2/TCC-atomic buffer
               unsigned long long* __restrict__ hbA,   // ws+4096: [2][256] agent/IF buffer
               unsigned* __restrict__ ctl)             // ws+8192: ready, elected, cnt[8], done
{
    // ---- XCD election: find 16 blocks co-located on one XCD (pigeonhole over 128) ----
    __shared__ int s_role;
    if (threadIdx.x == 0) {
        unsigned xcc;
        asm volatile("s_getreg_b32 %0, hwreg(HW_REG_XCC_ID, 0, 4)" : "=s"(xcc));
        unsigned* ready   = ctl + 0;
        unsigned* elected = ctl + 1;
        unsigned* cnt     = ctl + 2;   // [8]
        if (blockIdx.x == 0) {
            for (int i = 0; i < 8; ++i)
                __hip_atomic_store(cnt + i, 0u, __ATOMIC_RELAXED, __HIP_MEMORY_SCOPE_AGENT);
            __hip_atomic_store(elected, EMPTY_XCD, __ATOMIC_RELAXED, __HIP_MEMORY_SCOPE_AGENT);
            __hip_atomic_store(ctl + 10, 0u, __ATOMIC_RELAXED, __HIP_MEMORY_SCOPE_AGENT); // done
            __hip_atomic_store(ready, MAGIC_READY, __ATOMIC_RELEASE, __HIP_MEMORY_SCOPE_AGENT);
        }
        while (__hip_atomic_load(ready, __ATOMIC_ACQUIRE, __HIP_MEMORY_SCOPE_AGENT) != MAGIC_READY)
            asm volatile("s_sleep 1");
        unsigned r = __hip_atomic_fetch_add(cnt + xcc, 1u, __ATOMIC_RELAXED, __HIP_MEMORY_SCOPE_AGENT);
        if (r == 15u) {   // 16th arrival on this XCD: claim election (guaranteed to occur)
            unsigned expv = EMPTY_XCD;
            __hip_atomic_compare_exchange_strong(elected, &expv, xcc,
                __ATOMIC_RELAXED, __ATOMIC_RELAXED, __HIP_MEMORY_SCOPE_AGENT);
        }
        unsigned e;
        while ((e = __hip_atomic_load(elected, __ATOMIC_ACQUIRE, __HIP_MEMORY_SCOPE_AGENT)) == EMPTY_XCD)
            asm volatile("s_sleep 1");
        s_role = (xcc == e && r < 16u) ? (int)r : -1;
    }
    __syncthreads();
    const int w = s_role;          // role 0..15, or -1 = anti-DVFS spinner

    if (w < 0) {
        // Bystanders keep the clock governor awake with pure-register VALU work.
        float x0 = 1.0f, x1 = 2.0f, x2 = 3.0f, x3 = 4.0f;
        const float a = 1.0000001f, b = 1e-7f;
        const unsigned* done = ctl + 10;
        for (;;) {
            #pragma unroll 64
            for (int i = 0; i < 512; ++i) {
                x0 = fmaf(x0, a, b); x1 = fmaf(x1, a, b);
                x2 = fmaf(x2, a, b); x3 = fmaf(x3, a, b);
            }
            if (__hip_atomic_load(done, __ATOMIC_RELAXED, __HIP_MEMORY_SCOPE_AGENT) == DONE_MAGIC)
                break;
        }
        asm volatile("" :: "v"(x0 + x1 + x2 + x3));
        return;
    }

    // ---- scan body; h-exchange: plain-store -> L2, consumer reads via TCC atomics ----
    const int tid  = threadIdx.x;
    const int lane = tid & 63;
    const int wave = tid >> 6;         // 0..3
    const int rl   = lane >> 2;        // row-within-wave 0..15
    const int kq   = lane & 3;         // k-quarter 0..3
    const int r_wg = wave * 16 + rl;   // local gate-row 0..63
    const int unit_local = r_wg >> 2;  // 0..15
    const int gate = r_wg & 3;         // 0=i 1=f 2=cell 3=o
    const int unit = w * 16 + unit_local;      // global hidden unit 0..255
    const int grow = gate * 256 + unit;        // global gate row 0..1023
    const int kbase = kq * 64;

    float whh[64], wih[64];
    {
        const float* p = Whh + (size_t)grow * 256 + kbase;
        #pragma unroll
        for (int j = 0; j < 64; j += 4) {
            float4 q = *(const float4*)(p + j);
            whh[j] = q.x; whh[j+1] = q.y; whh[j+2] = q.z; whh[j+3] = q.w;
        }
        p = Wih + (size_t)grow * 256 + kbase;
        #pragma unroll
        for (int j = 0; j < 64; j += 4) {
            float4 q = *(const float4*)(p + j);
            wih[j] = q.x; wih[j+1] = q.y; wih[j+2] = q.z; wih[j+3] = q.w;
        }
    }
    const float bias = bih[grow] + bhh[grow];
    const bool owner = ((lane & 15) == 0);             // kq==0 && gate==0 -> owns `unit`
    const float act_scale = (gate == 2) ? 2.0f : 1.0f; // tanh vs sigmoid, single-exp form
    const float act_off   = (gate == 2) ? 1.0f : 0.0f;

    __shared__ float4 lds_h4[4][17];      // padded: conflict-free broadcast reads
    __shared__ float4 lds_e4[2][4][17];

    // publish h=0 with tag 0 into parity-0 of BOTH buffers (stale tags never match)
    if (owner) {
        st_u64(hbL + unit, 0ull);
        __hip_atomic_store(hbA + unit, 0ull, __ATOMIC_RELAXED, __HIP_MEMORY_SCOPE_AGENT);
    }
    if (wave == 1) {
        int tk = tokens[0];
        float4 e = *(const float4*)(emb + (size_t)tk * 256 + lane * 4);
        lds_e4[0][lane >> 4][lane & 15] = e;
    }
    float c = 0.0f;
    bool useL2 = true;                 // sticky per-lane fallback flag (wave 0 only)
    unsigned long long pk_prev = 0ull; // wave-0 owners: deferred hbA publish (tag t at top of iter t)
    asm volatile("s_waitcnt vmcnt(0)" ::: "memory");   // initial publishes committed
    __syncthreads();

    for (int t = 0; t < T_STEPS; ++t) {
        // wave 1: prefetch next embedding row (h-independent, off critical wave)
        if (wave == 1) {
            int tk = tokens[(t + 1 < T_STEPS) ? t + 1 : t];
            float4 e = *(const float4*)(emb + (size_t)tk * 256 + lane * 4);
            lds_e4[(t + 1) & 1][lane >> 4][lane & 15] = e;
        }
        // wave 0: issue the TCC-atomic poll batch NOW; flight hides under wih FMAs.
        // Deferred hbA publish goes AFTER the atomics so the first-check vmcnt(1)
        // retires exactly [prev hbL, prev out, a0..a3] and never the ~900cy IF ack.
        unsigned long long* hbp = hbL + (size_t)(t & 1) * 256 + lane * 4;
        unsigned long long q0, q1, q2, q3;
        if (wave == 0) {
            if (useL2) at4_issue(hbp, q0, q1, q2, q3);
            if (owner)
                __hip_atomic_store(hbA + (size_t)(t & 1) * 256 + unit, pk_prev,
                                   __ATOMIC_RELAXED, __HIP_MEMORY_SCOPE_AGENT);
        }
        // input contribution: wih . emb_t (h-independent), 4 independent chains
        float aA = 0.0f, aB = 0.0f, aC = 0.0f, aD = 0.0f;
        {
            const float4* eb = lds_e4[t & 1][kq];
            #pragma unroll
            for (int i = 0; i < 16; i += 4) {
                float4 v0 = eb[i], v1 = eb[i+1], v2 = eb[i+2], v3 = eb[i+3];
                aA = fmaf(wih[4*i+ 0], v0.x, aA); aA = fmaf(wih[4*i+ 1], v0.y, aA);
                aA = fmaf(wih[4*i+ 2], v0.z, aA); aA = fmaf(wih[4*i+ 3], v0.w, aA);
                aB = fmaf(wih[4*i+ 4], v1.x, aB); aB = fmaf(wih[4*i+ 5], v1.y, aB);
                aB = fmaf(wih[4*i+ 6], v1.z, aB); aB = fmaf(wih[4*i+ 7], v1.w, aB);
                aC = fmaf(wih[4*i+ 8], v2.x, aC); aC = fmaf(wih[4*i+ 9], v2.y, aC);
                aC = fmaf(wih[4*i+10], v2.z, aC); aC = fmaf(wih[4*i+11], v2.w, aC);
                aD = fmaf(wih[4*i+12], v3.x, aD); aD = fmaf(wih[4*i+13], v3.y, aD);
                aD = fmaf(wih[4*i+14], v3.z, aD); aD = fmaf(wih[4*i+15], v3.w, aD);
            }
        }
        // wave 0 checks its 4 (h, tag) pairs: TCC-atomic path bounded, sticky agent fallback
        if (wave == 0) {
            const unsigned int tt = (unsigned int)t;
            bool got = false;
            if (useL2) {
                vm_wait1_bind(q0, q1, q2, q3);     // precise: atomics retired, hbA may fly
                const int smax = (t == 0) ? SPIN_T0 : SPIN_RUN;
                int n = 0;
                for (;;) {
                    if (((unsigned int)(q0 >> 32) == tt) & ((unsigned int)(q1 >> 32) == tt) &
                        ((unsigned int)(q2 >> 32) == tt) & ((unsigned int)(q3 >> 32) == tt)) {
                        got = true; break;
                    }
                    if (++n > smax) { useL2 = false; break; }   // never hang on the TCC model
                    at4_issue(hbp, q0, q1, q2, q3);
                    vm_wait0_bind(q0, q1, q2, q3);
                }
            }
            if (!got) {   // proven agent/IF path (baseline formulation, 12.8 ms floor)
                const unsigned long long* ha = hbA + (size_t)(t & 1) * 256 + lane * 4;
                for (;;) {
                    q0 = __hip_atomic_load(ha + 0, __ATOMIC_RELAXED, __HIP_MEMORY_SCOPE_AGENT);
                    q1 = __hip_atomic_load(ha + 1, __ATOMIC_RELAXED, __HIP_MEMORY_SCOPE_AGENT);
                    q2 = __hip_atomic_load(ha + 2, __ATOMIC_RELAXED, __HIP_MEMORY_SCOPE_AGENT);
                    q3 = __hip_atomic_load(ha + 3, __ATOMIC_RELAXED, __HIP_MEMORY_SCOPE_AGENT);
                    if (((unsigned int)(q0 >> 32) == tt) & ((unsigned int)(q1 >> 32) == tt) &
                        ((unsigned int)(q2 >> 32) == tt) & ((unsigned int)(q3 >> 32) == tt))
                        break;
                }
            }
            union { unsigned int i; float f; } a, b, cc, d;
            a.i = (unsigned int)q0; b.i = (unsigned int)q1;
            cc.i = (unsigned int)q2; d.i = (unsigned int)q3;
            lds_h4[lane >> 4][lane & 15] = make_float4(a.f, b.f, cc.f, d.f);
        }
        __syncthreads();   // the only barrier per step
        // recurrent contribution: whh . h — 4 independent chains
        {
            const float4* hq = lds_h4[kq];
            #pragma unroll
            for (int i = 0; i < 16; i += 4) {
                float4 v0 = hq[i], v1 = hq[i+1], v2 = hq[i+2], v3 = hq[i+3];
                aA = fmaf(whh[4*i+ 0], v0.x, aA); aA = fmaf(whh[4*i+ 1], v0.y, aA);
                aA = fmaf(whh[4*i+ 2], v0.z, aA); aA = fmaf(whh[4*i+ 3], v0.w, aA);
                aB = fmaf(whh[4*i+ 4], v1.x, aB); aB = fmaf(whh[4*i+ 5], v1.y, aB);
                aB = fmaf(whh[4*i+ 6], v1.z, aB); aB = fmaf(whh[4*i+ 7], v1.w, aB);
                aC = fmaf(whh[4*i+ 8], v2.x, aC); aC = fmaf(whh[4*i+ 9], v2.y, aC);
                aC = fmaf(whh[4*i+10], v2.z, aC); aC = fmaf(whh[4*i+11], v2.w, aC);
                aD = fmaf(whh[4*i+12], v3.x, aD); aD = fmaf(whh[4*i+13], v3.y, aD);
                aD = fmaf(whh[4*i+14], v3.z, aD); aD = fmaf(whh[4*i+15], v3.w, aD);
            }
        }
        float acc = (aA + aB) + (aC + aD);
        // butterfly reduce across the 4 k-quarter lanes
        acc += __shfl_xor(acc, 1, 64);
        acc += __shfl_xor(acc, 2, 64);
        acc += bias;
        // per-gate nonlinearity applied IN PARALLEL before the gather
        float ex = __expf(-act_scale * acc);
        float av = act_scale / (1.0f + ex) - act_off;  // sigm for gates 0/1/3, tanh for 2
        const int base = lane & 48;
        float fv = __shfl(av, base + 4,  64);
        float gv = __shfl(av, base + 8,  64);
        float ov = __shfl(av, base + 12, 64);
        if (owner) {
            c = fmaf(fv, c, av * gv);                  // av == i-gate on owner lanes
            float h_out = ov * tanh_fast(c);           // single serial transcendental
            union { unsigned int i; float f; } u; u.f = h_out;
            unsigned long long pk =
                (((unsigned long long)(unsigned int)(t + 1)) << 32) | (unsigned long long)u.i;
            const size_t so = (size_t)((t + 1) & 1) * 256 + unit;
            st_u64(hbL + so, pk);                      // fast path: write-through to local L2
            out[(size_t)t * HID + unit] = h_out;
            if (t == T_STEPS - 1) {
                out[(size_t)T_STEPS * HID + unit]       = h_out;  // h_last
                out[(size_t)T_STEPS * HID + HID + unit] = c;      // c_last
            }
            if (wave == 0) pk_prev = pk;               // deferred hbA publish at next loop top
            else __hip_atomic_store(hbA + so, pk, __ATOMIC_RELAXED,
                                    __HIP_MEMORY_SCOPE_AGENT);    // fallback path (IF)
        }
        // Waves 1-3: commit hbL+out to L2 NOW (in-order retire; the trailing sc1 hbA
        // store is the 1 allowed outstanding op -> no ~900cy IF-ack stall). Hidden
        // under wave 0's poll. Wave 0's commit merges into its next first-check.
        if (wave != 0) asm volatile("s_waitcnt vmcnt(1)" ::: "memory");
        // no trailing barrier: spin discipline prevents WG-internal LDS races (R3 proof)
    }

    if (w == 0 && tid == 0) {
        // release the anti-DVFS spinners, then re-arm the election protocol
        __hip_atomic_store(ctl + 10, DONE_MAGIC, __ATOMIC_RELEASE, __HIP_MEMORY_SCOPE_AGENT);
        __hip_atomic_store(ctl + 0, 0u, __ATOMIC_RELAXED, __HIP_MEMORY_SCOPE_AGENT);
    }
}

extern "C" void kernel_launch(void* const* d_in, const int* in_sizes, int n_in,
                              void* d_out, int out_size, void* d_ws, size_t ws_size,
                              hipStream_t stream) {
    const int*   tokens = (const int*)d_in[0];
    const float* emb    = (const float*)d_in[1];
    const float* Wih    = (const float*)d_in[2];
    const float* Whh    = (const float*)d_in[3];
    const float* bih    = (const float*)d_in[4];
    const float* bhh    = (const float*)d_in[5];
    float* out = (float*)d_out;
    unsigned long long* hbL = (unsigned long long*)d_ws;                    // [2][256] u64
    unsigned long long* hbA = (unsigned long long*)((char*)d_ws + 4096);    // [2][256] u64
    unsigned* ctl = (unsigned*)((char*)d_ws + 8192);                        // ready, elected, cnt[8], done

    lstm_scan<<<NBLK, THREADS, 0, stream>>>(tokens, emb, Wih, Whh, bih, bhh, out, hbL, hbA, ctl);
}

// Round 4
// 29394.370 us; speedup vs baseline: 1.0348x; 1.0348x over previous
//
#include <hip/hip_runtime.h>

#define T_STEPS 8192
#define HID 256
#define NBLK 128      // dispatched; 16 co-located on one elected XCD participate
#define THREADS 256   // 4 waves
#define SPIN_T0   4096 // t==0 budget: covers inter-block startup skew
#define SPIN_RUN  64   // t>0 budget per step, then sticky fallback to agent path
#define SLOW_N    6    // a step needing >SLOW_N rounds counts as "slow"
#define SLOW_CAP  512  // this many slow steps -> TCC path is a net loss, demote

#define MAGIC_READY 0x13579BDFu
#define EMPTY_XCD   0xFFFFFFFFu
#define DONE_MAGIC  0x600DD00Eu

// 2/(1+e^-2x)-1 is inf-safe at both ends
__device__ __forceinline__ float tanh_fast(float x) { return 2.0f / (1.0f + __expf(-2.0f * x)) - 1.0f; }

// sc0 store: write-through commit to the XCD-local L2 (the TCC the consumer's
// atomics execute at). THE one-bit delta vs R3's plain store: without sc0 the
// value loitered ~10us before the TCC saw it (12 poll rounds/step).
__device__ __forceinline__ void st_u64_sc0(unsigned long long* p, unsigned long long v) {
    asm volatile("global_store_dwordx2 %0, %1, off sc0" :: "v"(p), "v"(v) : "memory");
}
// Consumer poll: 4x 8B atomic add-0 with return-old (sc0). Atomics execute AT THE
// TCC -> bypass L1 by construction, read the current L2 line, and do not punt to
// the IF (R2's sc1 mistake). Proven delivery mechanism (R3 passed on it).
__device__ __forceinline__ void at4_issue(unsigned long long* p,
                                          unsigned long long& a, unsigned long long& b,
                                          unsigned long long& c, unsigned long long& d) {
    unsigned long long z = 0ull;
    asm volatile(
        "global_atomic_add_x2 %0, %4, %5, off sc0\n\t"
        "global_atomic_add_x2 %1, %4, %5, off offset:8 sc0\n\t"
        "global_atomic_add_x2 %2, %4, %5, off offset:16 sc0\n\t"
        "global_atomic_add_x2 %3, %4, %5, off offset:24 sc0"
        : "=&v"(a), "=&v"(b), "=&v"(c), "=&v"(d)
        : "v"(p), "v"(z) : "memory");
}
// Waits with exact outstanding-counts, then dataflow-bind the asm outputs
// (rule-18: "memory" alone doesn't order register reads of asm outputs).
__device__ __forceinline__ void vm_wait1_bind(unsigned long long& a, unsigned long long& b,
                                              unsigned long long& c, unsigned long long& d) {
    asm volatile("s_waitcnt vmcnt(1)" ::: "memory");   // newest op (deferred hbA store) may fly
    __builtin_amdgcn_sched_barrier(0);
    asm volatile("" : "+v"(a), "+v"(b), "+v"(c), "+v"(d));
}
__device__ __forceinline__ void vm_wait0_bind(unsigned long long& a, unsigned long long& b,
                                              unsigned long long& c, unsigned long long& d) {
    asm volatile("s_waitcnt vmcnt(0)" ::: "memory");
    __builtin_amdgcn_sched_barrier(0);
    asm volatile("" : "+v"(a), "+v"(b), "+v"(c), "+v"(d));
}

__global__ __launch_bounds__(THREADS, 1)
void lstm_scan(const int* __restrict__ tokens,
               const float* __restrict__ emb,    // [V,256] fp32
               const float* __restrict__ Wih,    // [1024,256] fp32
               const float* __restrict__ Whh,    // [1024,256] fp32
               const float* __restrict__ bih,    // [1024]
               const float* __restrict__ bhh,    // [1024]
               float* __restrict__ out,          // [T*256 + 256 + 256] fp32
               unsigned long long* __restrict__ hbL,   // ws+0:    [2][256] L2/TCC exchange buffer
               unsigned long long* __restrict__ hbA,   // ws+4096: [2][256] agent/IF buffer
               unsigned* __restrict__ ctl)             // ws+8192: ready, elected, cnt[8], done
{
    // ---- XCD election: find 16 blocks co-located on one XCD (pigeonhole over 128) ----
    __shared__ int s_role;
    if (threadIdx.x == 0) {
        unsigned xcc;
        asm volatile("s_getreg_b32 %0, hwreg(HW_REG_XCC_ID, 0, 4)" : "=s"(xcc));
        unsigned* ready   = ctl + 0;
        unsigned* elected = ctl + 1;
        unsigned* cnt     = ctl + 2;   // [8]
        if (blockIdx.x == 0) {
            for (int i = 0; i < 8; ++i)
                __hip_atomic_store(cnt + i, 0u, __ATOMIC_RELAXED, __HIP_MEMORY_SCOPE_AGENT);
            __hip_atomic_store(elected, EMPTY_XCD, __ATOMIC_RELAXED, __HIP_MEMORY_SCOPE_AGENT);
            __hip_atomic_store(ctl + 10, 0u, __ATOMIC_RELAXED, __HIP_MEMORY_SCOPE_AGENT); // done
            __hip_atomic_store(ready, MAGIC_READY, __ATOMIC_RELEASE, __HIP_MEMORY_SCOPE_AGENT);
        }
        while (__hip_atomic_load(ready, __ATOMIC_ACQUIRE, __HIP_MEMORY_SCOPE_AGENT) != MAGIC_READY)
            asm volatile("s_sleep 1");
        unsigned r = __hip_atomic_fetch_add(cnt + xcc, 1u, __ATOMIC_RELAXED, __HIP_MEMORY_SCOPE_AGENT);
        if (r == 15u) {   // 16th arrival on this XCD: claim election (guaranteed to occur)
            unsigned expv = EMPTY_XCD;
            __hip_atomic_compare_exchange_strong(elected, &expv, xcc,
                __ATOMIC_RELAXED, __ATOMIC_RELAXED, __HIP_MEMORY_SCOPE_AGENT);
        }
        unsigned e;
        while ((e = __hip_atomic_load(elected, __ATOMIC_ACQUIRE, __HIP_MEMORY_SCOPE_AGENT)) == EMPTY_XCD)
            asm volatile("s_sleep 1");
        s_role = (xcc == e && r < 16u) ? (int)r : -1;
    }
    __syncthreads();
    const int w = s_role;          // role 0..15, or -1 = anti-DVFS spinner

    if (w < 0) {
        // Bystanders keep the clock governor awake with pure-register VALU work.
        float x0 = 1.0f, x1 = 2.0f, x2 = 3.0f, x3 = 4.0f;
        const float a = 1.0000001f, b = 1e-7f;
        const unsigned* done = ctl + 10;
        for (;;) {
            #pragma unroll 64
            for (int i = 0; i < 512; ++i) {
                x0 = fmaf(x0, a, b); x1 = fmaf(x1, a, b);
                x2 = fmaf(x2, a, b); x3 = fmaf(x3, a, b);
            }
            if (__hip_atomic_load(done, __ATOMIC_RELAXED, __HIP_MEMORY_SCOPE_AGENT) == DONE_MAGIC)
                break;
        }
        asm volatile("" :: "v"(x0 + x1 + x2 + x3));
        return;
    }

    // ---- scan body; h-exchange: sc0 store -> local L2, consumer reads via TCC atomics ----
    const int tid  = threadIdx.x;
    const int lane = tid & 63;
    const int wave = tid >> 6;         // 0..3
    const int rl   = lane >> 2;        // row-within-wave 0..15
    const int kq   = lane & 3;         // k-quarter 0..3
    const int r_wg = wave * 16 + rl;   // local gate-row 0..63
    const int unit_local = r_wg >> 2;  // 0..15
    const int gate = r_wg & 3;         // 0=i 1=f 2=cell 3=o
    const int unit = w * 16 + unit_local;      // global hidden unit 0..255
    const int grow = gate * 256 + unit;        // global gate row 0..1023
    const int kbase = kq * 64;

    float whh[64], wih[64];
    {
        const float* p = Whh + (size_t)grow * 256 + kbase;
        #pragma unroll
        for (int j = 0; j < 64; j += 4) {
            float4 q = *(const float4*)(p + j);
            whh[j] = q.x; whh[j+1] = q.y; whh[j+2] = q.z; whh[j+3] = q.w;
        }
        p = Wih + (size_t)grow * 256 + kbase;
        #pragma unroll
        for (int j = 0; j < 64; j += 4) {
            float4 q = *(const float4*)(p + j);
            wih[j] = q.x; wih[j+1] = q.y; wih[j+2] = q.z; wih[j+3] = q.w;
        }
    }
    const float bias = bih[grow] + bhh[grow];
    const bool owner = ((lane & 15) == 0);             // kq==0 && gate==0 -> owns `unit`
    const float act_scale = (gate == 2) ? 2.0f : 1.0f; // tanh vs sigmoid, single-exp form
    const float act_off   = (gate == 2) ? 1.0f : 0.0f;

    __shared__ float4 lds_h4[4][17];      // padded: conflict-free broadcast reads
    __shared__ float4 lds_e4[2][4][17];

    // publish h=0 with tag 0 into parity-0 of BOTH buffers (stale tags never match)
    if (owner) {
        st_u64_sc0(hbL + unit, 0ull);
        __hip_atomic_store(hbA + unit, 0ull, __ATOMIC_RELAXED, __HIP_MEMORY_SCOPE_AGENT);
    }
    if (wave == 1) {
        int tk = tokens[0];
        float4 e = *(const float4*)(emb + (size_t)tk * 256 + lane * 4);
        lds_e4[0][lane >> 4][lane & 15] = e;
    }
    float c = 0.0f;
    bool useL2 = true;                 // sticky per-lane fallback flag (wave 0 only)
    int  slow  = 0;                    // cumulative slow-success counter (wave 0 only)
    unsigned long long pk_prev = 0ull; // wave-0 owners: deferred hbA publish (tag t at top of iter t)
    __syncthreads();                   // barrier drains vmcnt -> initial publishes committed

    for (int t = 0; t < T_STEPS; ++t) {
        // wave 1: prefetch next embedding row (h-independent, off critical wave)
        if (wave == 1) {
            int tk = tokens[(t + 1 < T_STEPS) ? t + 1 : t];
            float4 e = *(const float4*)(emb + (size_t)tk * 256 + lane * 4);
            lds_e4[(t + 1) & 1][lane >> 4][lane & 15] = e;
        }
        // wave 0: issue the TCC-atomic poll batch NOW; flight hides under wih FMAs.
        // Deferred hbA publish goes AFTER the atomics so first-check vmcnt(1) leaves
        // exactly the newest op (hbA, ~900cy IF ack) outstanding -- never gates.
        unsigned long long* hbp = hbL + (size_t)(t & 1) * 256 + lane * 4;
        unsigned long long q0, q1, q2, q3;
        if (wave == 0) {
            if (useL2) at4_issue(hbp, q0, q1, q2, q3);
            if (owner)
                __hip_atomic_store(hbA + (size_t)(t & 1) * 256 + unit, pk_prev,
                                   __ATOMIC_RELAXED, __HIP_MEMORY_SCOPE_AGENT);
        }
        // input contribution: wih . emb_t (h-independent), 4 independent chains
        float aA = 0.0f, aB = 0.0f, aC = 0.0f, aD = 0.0f;
        {
            const float4* eb = lds_e4[t & 1][kq];
            #pragma unroll
            for (int i = 0; i < 16; i += 4) {
                float4 v0 = eb[i], v1 = eb[i+1], v2 = eb[i+2], v3 = eb[i+3];
                aA = fmaf(wih[4*i+ 0], v0.x, aA); aA = fmaf(wih[4*i+ 1], v0.y, aA);
                aA = fmaf(wih[4*i+ 2], v0.z, aA); aA = fmaf(wih[4*i+ 3], v0.w, aA);
                aB = fmaf(wih[4*i+ 4], v1.x, aB); aB = fmaf(wih[4*i+ 5], v1.y, aB);
                aB = fmaf(wih[4*i+ 6], v1.z, aB); aB = fmaf(wih[4*i+ 7], v1.w, aB);
                aC = fmaf(wih[4*i+ 8], v2.x, aC); aC = fmaf(wih[4*i+ 9], v2.y, aC);
                aC = fmaf(wih[4*i+10], v2.z, aC); aC = fmaf(wih[4*i+11], v2.w, aC);
                aD = fmaf(wih[4*i+12], v3.x, aD); aD = fmaf(wih[4*i+13], v3.y, aD);
                aD = fmaf(wih[4*i+14], v3.z, aD); aD = fmaf(wih[4*i+15], v3.w, aD);
            }
        }
        // wave 0 checks its 4 (h, tag) pairs: TCC path bounded + slow-guarded,
        // sticky agent fallback (baseline-proven 12.8ms floor)
        if (wave == 0) {
            const unsigned int tt = (unsigned int)t;
            bool got = false;
            if (useL2) {
                vm_wait1_bind(q0, q1, q2, q3);     // atomics retired; deferred hbA may fly
                const int smax = (t == 0) ? SPIN_T0 : SPIN_RUN;
                int n = 0;
                for (;;) {
                    if (((unsigned int)(q0 >> 32) == tt) & ((unsigned int)(q1 >> 32) == tt) &
                        ((unsigned int)(q2 >> 32) == tt) & ((unsigned int)(q3 >> 32) == tt)) {
                        got = true; break;
                    }
                    if (++n > smax) { useL2 = false; break; }   // never hang on the TCC model
                    at4_issue(hbp, q0, q1, q2, q3);
                    vm_wait0_bind(q0, q1, q2, q3);
                }
                // R3 lesson: "delivers but slowly" stays under the per-step budget
                // forever and loses to the agent path. Demote on cumulative evidence.
                if (got && t > 0 && n > SLOW_N && ++slow > SLOW_CAP) useL2 = false;
            }
            if (!got) {   // proven agent/IF path (baseline formulation)
                const unsigned long long* ha = hbA + (size_t)(t & 1) * 256 + lane * 4;
                for (;;) {
                    q0 = __hip_atomic_load(ha + 0, __ATOMIC_RELAXED, __HIP_MEMORY_SCOPE_AGENT);
                    q1 = __hip_atomic_load(ha + 1, __ATOMIC_RELAXED, __HIP_MEMORY_SCOPE_AGENT);
                    q2 = __hip_atomic_load(ha + 2, __ATOMIC_RELAXED, __HIP_MEMORY_SCOPE_AGENT);
                    q3 = __hip_atomic_load(ha + 3, __ATOMIC_RELAXED, __HIP_MEMORY_SCOPE_AGENT);
                    if (((unsigned int)(q0 >> 32) == tt) & ((unsigned int)(q1 >> 32) == tt) &
                        ((unsigned int)(q2 >> 32) == tt) & ((unsigned int)(q3 >> 32) == tt))
                        break;
                }
            }
            union { unsigned int i; float f; } a, b, cc, d;
            a.i = (unsigned int)q0; b.i = (unsigned int)q1;
            cc.i = (unsigned int)q2; d.i = (unsigned int)q3;
            lds_h4[lane >> 4][lane & 15] = make_float4(a.f, b.f, cc.f, d.f);
        }
        __syncthreads();   // the only barrier per step
        // recurrent contribution: whh . h — 4 independent chains
        {
            const float4* hq = lds_h4[kq];
            #pragma unroll
            for (int i = 0; i < 16; i += 4) {
                float4 v0 = hq[i], v1 = hq[i+1], v2 = hq[i+2], v3 = hq[i+3];
                aA = fmaf(whh[4*i+ 0], v0.x, aA); aA = fmaf(whh[4*i+ 1], v0.y, aA);
                aA = fmaf(whh[4*i+ 2], v0.z, aA); aA = fmaf(whh[4*i+ 3], v0.w, aA);
                aB = fmaf(whh[4*i+ 4], v1.x, aB); aB = fmaf(whh[4*i+ 5], v1.y, aB);
                aB = fmaf(whh[4*i+ 6], v1.z, aB); aB = fmaf(whh[4*i+ 7], v1.w, aB);
                aC = fmaf(whh[4*i+ 8], v2.x, aC); aC = fmaf(whh[4*i+ 9], v2.y, aC);
                aC = fmaf(whh[4*i+10], v2.z, aC); aC = fmaf(whh[4*i+11], v2.w, aC);
                aD = fmaf(whh[4*i+12], v3.x, aD); aD = fmaf(whh[4*i+13], v3.y, aD);
                aD = fmaf(whh[4*i+14], v3.z, aD); aD = fmaf(whh[4*i+15], v3.w, aD);
            }
        }
        float acc = (aA + aB) + (aC + aD);
        // butterfly reduce across the 4 k-quarter lanes
        acc += __shfl_xor(acc, 1, 64);
        acc += __shfl_xor(acc, 2, 64);
        acc += bias;
        // per-gate nonlinearity applied IN PARALLEL before the gather
        float ex = __expf(-act_scale * acc);
        float av = act_scale / (1.0f + ex) - act_off;  // sigm for gates 0/1/3, tanh for 2
        const int base = lane & 48;
        float fv = __shfl(av, base + 4,  64);
        float gv = __shfl(av, base + 8,  64);
        float ov = __shfl(av, base + 12, 64);
        if (owner) {
            c = fmaf(fv, c, av * gv);                  // av == i-gate on owner lanes
            float h_out = ov * tanh_fast(c);           // single serial transcendental
            union { unsigned int i; float f; } u; u.f = h_out;
            unsigned long long pk =
                (((unsigned long long)(unsigned int)(t + 1)) << 32) | (unsigned long long)u.i;
            const size_t so = (size_t)((t + 1) & 1) * 256 + unit;
            st_u64_sc0(hbL + so, pk);                  // fast path: sc0 commit to local L2/TCC
            if (wave == 0) pk_prev = pk;               // deferred hbA publish at next loop top
            else __hip_atomic_store(hbA + so, pk, __ATOMIC_RELAXED,
                                    __HIP_MEMORY_SCOPE_AGENT);    // fallback path (IF)
            out[(size_t)t * HID + unit] = h_out;
            if (t == T_STEPS - 1) {
                out[(size_t)T_STEPS * HID + unit]       = h_out;  // h_last
                out[(size_t)T_STEPS * HID + HID + unit] = c;      // c_last
            }
        }
        // NO producer drains: stores retire in the background; the TCC serializes
        // store vs atomic on the same line. R2/R3 measured forced drains as pure cost.
        // no trailing barrier: spin discipline prevents WG-internal LDS races (R3 proof)
    }

    if (w == 0 && tid == 0) {
        // release the anti-DVFS spinners, then re-arm the election protocol
        __hip_atomic_store(ctl + 10, DONE_MAGIC, __ATOMIC_RELEASE, __HIP_MEMORY_SCOPE_AGENT);
        __hip_atomic_store(ctl + 0, 0u, __ATOMIC_RELAXED, __HIP_MEMORY_SCOPE_AGENT);
    }
}

extern "C" void kernel_launch(void* const* d_in, const int* in_sizes, int n_in,
                              void* d_out, int out_size, void* d_ws, size_t ws_size,
                              hipStream_t stream) {
    const int*   tokens = (const int*)d_in[0];
    const float* emb    = (const float*)d_in[1];
    const float* Wih    = (const float*)d_in[2];
    const float* Whh    = (const float*)d_in[3];
    const float* bih    = (const float*)d_in[4];
    const float* bhh    = (const float*)d_in[5];
    float* out = (float*)d_out;
    unsigned long long* hbL = (unsigned long long*)d_ws;                    // [2][256] u64
    unsigned long long* hbA = (unsigned long long*)((char*)d_ws + 4096);    // [2][256] u64
    unsigned* ctl = (unsigned*)((char*)d_ws + 8192);                        // ready, elected, cnt[8], done

    lstm_scan<<<NBLK, THREADS, 0, stream>>>(tokens, emb, Wih, Whh, bih, bhh, out, hbL, hbA, ctl);
}

// Round 5
// 11768.909 us; speedup vs baseline: 2.5846x; 2.4976x over previous
//
#include <hip/hip_runtime.h>

#define T_STEPS 8192
#define HID 256
#define NBLK 128      // dispatched; 16 co-located on one elected XCD participate
#define THREADS 256   // 4 waves
#define SPIN_T0   4096 // t==0 budget: covers inter-block startup skew
#define SPIN_RUN  64   // t>0 budget per step, then sticky fallback to agent path
#define SLOW_N    6    // a step needing >SLOW_N rounds counts as "slow"
#define SLOW_CAP  512  // this many slow steps -> L2 path is a net loss, demote

#define MAGIC_READY 0x13579BDFu
#define EMPTY_XCD   0xFFFFFFFFu
#define DONE_MAGIC  0x600DD00Eu

// 2/(1+e^-2x)-1 is inf-safe at both ends
__device__ __forceinline__ float tanh_fast(float x) { return 2.0f / (1.0f + __expf(-2.0f * x)) - 1.0f; }

// sc0 store: write-through commit to the XCD-local L2. (R4 confirmed this is NOT
// visible to MALL-side readers until writeback -- so the READER must come to the
// local L2, not the other way around.)
__device__ __forceinline__ void st_u64_sc0(unsigned long long* p, unsigned long long v) {
    asm volatile("global_store_dwordx2 %0, %1, off sc0" :: "v"(p), "v"(v) : "memory");
}
// Invalidate the CU's vector L1 (write-through -> no data loss). This is the piece
// every prior sc0-load attempt was missing: without it a spin loop re-reads its own
// stale L1 line forever. After inv, an sc0 load MUST be served by the local L2 --
// exactly where the producers' sc0 stores committed.
__device__ __forceinline__ void inv_l1() {
    asm volatile("buffer_inv sc0" ::: "memory");
}
// Issue-only 4x8B sc0 loads (no wait): caller overlaps compute with flight time.
__device__ __forceinline__ void ld4_issue_sc0(const unsigned long long* p,
                                              unsigned long long& a, unsigned long long& b,
                                              unsigned long long& c, unsigned long long& d) {
    asm volatile(
        "global_load_dwordx2 %0, %4, off sc0\n\t"
        "global_load_dwordx2 %1, %4, off offset:8 sc0\n\t"
        "global_load_dwordx2 %2, %4, off offset:16 sc0\n\t"
        "global_load_dwordx2 %3, %4, off offset:24 sc0"
        : "=&v"(a), "=&v"(b), "=&v"(c), "=&v"(d)
        : "v"(p) : "memory");
}
// Waits with exact outstanding-counts, then dataflow-bind the asm outputs
// (rule-18: "memory" alone doesn't order register reads of asm outputs).
__device__ __forceinline__ void vm_wait1_bind(unsigned long long& a, unsigned long long& b,
                                              unsigned long long& c, unsigned long long& d) {
    asm volatile("s_waitcnt vmcnt(1)" ::: "memory");   // newest op (deferred hbA store) may fly
    __builtin_amdgcn_sched_barrier(0);
    asm volatile("" : "+v"(a), "+v"(b), "+v"(c), "+v"(d));
}
__device__ __forceinline__ void vm_wait0_bind(unsigned long long& a, unsigned long long& b,
                                              unsigned long long& c, unsigned long long& d) {
    asm volatile("s_waitcnt vmcnt(0)" ::: "memory");
    __builtin_amdgcn_sched_barrier(0);
    asm volatile("" : "+v"(a), "+v"(b), "+v"(c), "+v"(d));
}

__global__ __launch_bounds__(THREADS, 1)
void lstm_scan(const int* __restrict__ tokens,
               const float* __restrict__ emb,    // [V,256] fp32
               const float* __restrict__ Wih,    // [1024,256] fp32
               const float* __restrict__ Whh,    // [1024,256] fp32
               const float* __restrict__ bih,    // [1024]
               const float* __restrict__ bhh,    // [1024]
               float* __restrict__ out,          // [T*256 + 256 + 256] fp32
               unsigned long long* __restrict__ hbL,   // ws+0:    [2][256] local-L2 exchange buffer
               unsigned long long* __restrict__ hbA,   // ws+4096: [2][256] agent/IF buffer
               unsigned* __restrict__ ctl)             // ws+8192: ready, elected, cnt[8], done
{
    // ---- XCD election: find 16 blocks co-located on one XCD (pigeonhole over 128) ----
    __shared__ int s_role;
    if (threadIdx.x == 0) {
        unsigned xcc;
        asm volatile("s_getreg_b32 %0, hwreg(HW_REG_XCC_ID, 0, 4)" : "=s"(xcc));
        unsigned* ready   = ctl + 0;
        unsigned* elected = ctl + 1;
        unsigned* cnt     = ctl + 2;   // [8]
        if (blockIdx.x == 0) {
            for (int i = 0; i < 8; ++i)
                __hip_atomic_store(cnt + i, 0u, __ATOMIC_RELAXED, __HIP_MEMORY_SCOPE_AGENT);
            __hip_atomic_store(elected, EMPTY_XCD, __ATOMIC_RELAXED, __HIP_MEMORY_SCOPE_AGENT);
            __hip_atomic_store(ctl + 10, 0u, __ATOMIC_RELAXED, __HIP_MEMORY_SCOPE_AGENT); // done
            __hip_atomic_store(ready, MAGIC_READY, __ATOMIC_RELEASE, __HIP_MEMORY_SCOPE_AGENT);
        }
        while (__hip_atomic_load(ready, __ATOMIC_ACQUIRE, __HIP_MEMORY_SCOPE_AGENT) != MAGIC_READY)
            asm volatile("s_sleep 1");
        unsigned r = __hip_atomic_fetch_add(cnt + xcc, 1u, __ATOMIC_RELAXED, __HIP_MEMORY_SCOPE_AGENT);
        if (r == 15u) {   // 16th arrival on this XCD: claim election (guaranteed to occur)
            unsigned expv = EMPTY_XCD;
            __hip_atomic_compare_exchange_strong(elected, &expv, xcc,
                __ATOMIC_RELAXED, __ATOMIC_RELAXED, __HIP_MEMORY_SCOPE_AGENT);
        }
        unsigned e;
        while ((e = __hip_atomic_load(elected, __ATOMIC_ACQUIRE, __HIP_MEMORY_SCOPE_AGENT)) == EMPTY_XCD)
            asm volatile("s_sleep 1");
        s_role = (xcc == e && r < 16u) ? (int)r : -1;
    }
    __syncthreads();
    const int w = s_role;          // role 0..15, or -1 = anti-DVFS spinner

    if (w < 0) {
        // Bystanders keep the clock governor awake with pure-register VALU work.
        float x0 = 1.0f, x1 = 2.0f, x2 = 3.0f, x3 = 4.0f;
        const float a = 1.0000001f, b = 1e-7f;
        const unsigned* done = ctl + 10;
        for (;;) {
            #pragma unroll 64
            for (int i = 0; i < 512; ++i) {
                x0 = fmaf(x0, a, b); x1 = fmaf(x1, a, b);
                x2 = fmaf(x2, a, b); x3 = fmaf(x3, a, b);
            }
            if (__hip_atomic_load(done, __ATOMIC_RELAXED, __HIP_MEMORY_SCOPE_AGENT) == DONE_MAGIC)
                break;
        }
        asm volatile("" :: "v"(x0 + x1 + x2 + x3));
        return;
    }

    // ---- scan body; h-exchange: sc0 store -> local L2; consumer: L1-inv + sc0 load ----
    const int tid  = threadIdx.x;
    const int lane = tid & 63;
    const int wave = tid >> 6;         // 0..3
    const int rl   = lane >> 2;        // row-within-wave 0..15
    const int kq   = lane & 3;         // k-quarter 0..3
    const int r_wg = wave * 16 + rl;   // local gate-row 0..63
    const int unit_local = r_wg >> 2;  // 0..15
    const int gate = r_wg & 3;         // 0=i 1=f 2=cell 3=o
    const int unit = w * 16 + unit_local;      // global hidden unit 0..255
    const int grow = gate * 256 + unit;        // global gate row 0..1023
    const int kbase = kq * 64;

    float whh[64], wih[64];
    {
        const float* p = Whh + (size_t)grow * 256 + kbase;
        #pragma unroll
        for (int j = 0; j < 64; j += 4) {
            float4 q = *(const float4*)(p + j);
            whh[j] = q.x; whh[j+1] = q.y; whh[j+2] = q.z; whh[j+3] = q.w;
        }
        p = Wih + (size_t)grow * 256 + kbase;
        #pragma unroll
        for (int j = 0; j < 64; j += 4) {
            float4 q = *(const float4*)(p + j);
            wih[j] = q.x; wih[j+1] = q.y; wih[j+2] = q.z; wih[j+3] = q.w;
        }
    }
    const float bias = bih[grow] + bhh[grow];
    const bool owner = ((lane & 15) == 0);             // kq==0 && gate==0 -> owns `unit`
    const float act_scale = (gate == 2) ? 2.0f : 1.0f; // tanh vs sigmoid, single-exp form
    const float act_off   = (gate == 2) ? 1.0f : 0.0f;

    __shared__ float4 lds_h4[4][17];      // padded: conflict-free broadcast reads
    __shared__ float4 lds_e4[2][4][17];

    // publish h=0 with tag 0 into parity-0 of BOTH buffers (stale tags never match)
    if (owner) {
        st_u64_sc0(hbL + unit, 0ull);
        __hip_atomic_store(hbA + unit, 0ull, __ATOMIC_RELAXED, __HIP_MEMORY_SCOPE_AGENT);
    }
    if (wave == 1) {
        int tk = tokens[0];
        float4 e = *(const float4*)(emb + (size_t)tk * 256 + lane * 4);
        lds_e4[0][lane >> 4][lane & 15] = e;
    }
    float c = 0.0f;
    bool useL2 = true;                 // sticky per-lane fallback flag (wave 0 only)
    int  slow  = 0;                    // cumulative slow-success counter (wave 0 only)
    unsigned long long pk_prev = 0ull; // wave-0 owners: deferred hbA publish (tag t at top of iter t)
    __syncthreads();                   // barrier drains vmcnt -> initial publishes committed

    for (int t = 0; t < T_STEPS; ++t) {
        // wave 1: prefetch next embedding row (h-independent, off critical wave)
        if (wave == 1) {
            int tk = tokens[(t + 1 < T_STEPS) ? t + 1 : t];
            float4 e = *(const float4*)(emb + (size_t)tk * 256 + lane * 4);
            lds_e4[(t + 1) & 1][lane >> 4][lane & 15] = e;
        }
        // wave 0: L1-invalidate (this parity's lines are stale from 2 steps ago),
        // then issue the sc0 poll batch NOW; flight hides under the wih FMAs.
        // Deferred hbA publish goes AFTER the loads so first-check vmcnt(1) leaves
        // exactly the newest op (hbA, ~900cy IF ack) outstanding -- never gates.
        unsigned long long* hbp = hbL + (size_t)(t & 1) * 256 + lane * 4;
        unsigned long long q0, q1, q2, q3;
        if (wave == 0) {
            if (useL2) {
                inv_l1();
                ld4_issue_sc0(hbp, q0, q1, q2, q3);
            }
            if (owner)
                __hip_atomic_store(hbA + (size_t)(t & 1) * 256 + unit, pk_prev,
                                   __ATOMIC_RELAXED, __HIP_MEMORY_SCOPE_AGENT);
        }
        // input contribution: wih . emb_t (h-independent), 4 independent chains
        float aA = 0.0f, aB = 0.0f, aC = 0.0f, aD = 0.0f;
        {
            const float4* eb = lds_e4[t & 1][kq];
            #pragma unroll
            for (int i = 0; i < 16; i += 4) {
                float4 v0 = eb[i], v1 = eb[i+1], v2 = eb[i+2], v3 = eb[i+3];
                aA = fmaf(wih[4*i+ 0], v0.x, aA); aA = fmaf(wih[4*i+ 1], v0.y, aA);
                aA = fmaf(wih[4*i+ 2], v0.z, aA); aA = fmaf(wih[4*i+ 3], v0.w, aA);
                aB = fmaf(wih[4*i+ 4], v1.x, aB); aB = fmaf(wih[4*i+ 5], v1.y, aB);
                aB = fmaf(wih[4*i+ 6], v1.z, aB); aB = fmaf(wih[4*i+ 7], v1.w, aB);
                aC = fmaf(wih[4*i+ 8], v2.x, aC); aC = fmaf(wih[4*i+ 9], v2.y, aC);
                aC = fmaf(wih[4*i+10], v2.z, aC); aC = fmaf(wih[4*i+11], v2.w, aC);
                aD = fmaf(wih[4*i+12], v3.x, aD); aD = fmaf(wih[4*i+13], v3.y, aD);
                aD = fmaf(wih[4*i+14], v3.z, aD); aD = fmaf(wih[4*i+15], v3.w, aD);
            }
        }
        // wave 0 checks its 4 (h, tag) pairs: inv+sc0 rounds bounded + slow-guarded,
        // sticky agent fallback (baseline-proven 12.8ms floor)
        if (wave == 0) {
            const unsigned int tt = (unsigned int)t;
            bool got = false;
            if (useL2) {
                vm_wait1_bind(q0, q1, q2, q3);     // loads retired; deferred hbA may fly
                const int smax = (t == 0) ? SPIN_T0 : SPIN_RUN;
                int n = 0;
                for (;;) {
                    if (((unsigned int)(q0 >> 32) == tt) & ((unsigned int)(q1 >> 32) == tt) &
                        ((unsigned int)(q2 >> 32) == tt) & ((unsigned int)(q3 >> 32) == tt)) {
                        got = true; break;
                    }
                    if (++n > smax) { useL2 = false; break; }   // never hang on this model
                    inv_l1();                                   // drop stale L1 line
                    ld4_issue_sc0(hbp, q0, q1, q2, q3);         // re-read from local L2
                    vm_wait0_bind(q0, q1, q2, q3);
                }
                // R3 lesson: "delivers but slowly" stays under the per-step budget
                // forever and loses to the agent path. Demote on cumulative evidence.
                if (got && t > 0 && n > SLOW_N && ++slow > SLOW_CAP) useL2 = false;
            }
            if (!got) {   // proven agent/IF path (baseline formulation)
                const unsigned long long* ha = hbA + (size_t)(t & 1) * 256 + lane * 4;
                for (;;) {
                    q0 = __hip_atomic_load(ha + 0, __ATOMIC_RELAXED, __HIP_MEMORY_SCOPE_AGENT);
                    q1 = __hip_atomic_load(ha + 1, __ATOMIC_RELAXED, __HIP_MEMORY_SCOPE_AGENT);
                    q2 = __hip_atomic_load(ha + 2, __ATOMIC_RELAXED, __HIP_MEMORY_SCOPE_AGENT);
                    q3 = __hip_atomic_load(ha + 3, __ATOMIC_RELAXED, __HIP_MEMORY_SCOPE_AGENT);
                    if (((unsigned int)(q0 >> 32) == tt) & ((unsigned int)(q1 >> 32) == tt) &
                        ((unsigned int)(q2 >> 32) == tt) & ((unsigned int)(q3 >> 32) == tt))
                        break;
                }
            }
            union { unsigned int i; float f; } a, b, cc, d;
            a.i = (unsigned int)q0; b.i = (unsigned int)q1;
            cc.i = (unsigned int)q2; d.i = (unsigned int)q3;
            lds_h4[lane >> 4][lane & 15] = make_float4(a.f, b.f, cc.f, d.f);
        }
        __syncthreads();   // the only barrier per step
        // recurrent contribution: whh . h — 4 independent chains
        {
            const float4* hq = lds_h4[kq];
            #pragma unroll
            for (int i = 0; i < 16; i += 4) {
                float4 v0 = hq[i], v1 = hq[i+1], v2 = hq[i+2], v3 = hq[i+3];
                aA = fmaf(whh[4*i+ 0], v0.x, aA); aA = fmaf(whh[4*i+ 1], v0.y, aA);
                aA = fmaf(whh[4*i+ 2], v0.z, aA); aA = fmaf(whh[4*i+ 3], v0.w, aA);
                aB = fmaf(whh[4*i+ 4], v1.x, aB); aB = fmaf(whh[4*i+ 5], v1.y, aB);
                aB = fmaf(whh[4*i+ 6], v1.z, aB); aB = fmaf(whh[4*i+ 7], v1.w, aB);
                aC = fmaf(whh[4*i+ 8], v2.x, aC); aC = fmaf(whh[4*i+ 9], v2.y, aC);
                aC = fmaf(whh[4*i+10], v2.z, aC); aC = fmaf(whh[4*i+11], v2.w, aC);
                aD = fmaf(whh[4*i+12], v3.x, aD); aD = fmaf(whh[4*i+13], v3.y, aD);
                aD = fmaf(whh[4*i+14], v3.z, aD); aD = fmaf(whh[4*i+15], v3.w, aD);
            }
        }
        float acc = (aA + aB) + (aC + aD);
        // butterfly reduce across the 4 k-quarter lanes
        acc += __shfl_xor(acc, 1, 64);
        acc += __shfl_xor(acc, 2, 64);
        acc += bias;
        // per-gate nonlinearity applied IN PARALLEL before the gather
        float ex = __expf(-act_scale * acc);
        float av = act_scale / (1.0f + ex) - act_off;  // sigm for gates 0/1/3, tanh for 2
        const int base = lane & 48;
        float fv = __shfl(av, base + 4,  64);
        float gv = __shfl(av, base + 8,  64);
        float ov = __shfl(av, base + 12, 64);
        if (owner) {
            c = fmaf(fv, c, av * gv);                  // av == i-gate on owner lanes
            float h_out = ov * tanh_fast(c);           // single serial transcendental
            union { unsigned int i; float f; } u; u.f = h_out;
            unsigned long long pk =
                (((unsigned long long)(unsigned int)(t + 1)) << 32) | (unsigned long long)u.i;
            const size_t so = (size_t)((t + 1) & 1) * 256 + unit;
            st_u64_sc0(hbL + so, pk);                  // fast path: commit to local L2
            if (wave == 0) pk_prev = pk;               // deferred hbA publish at next loop top
            else __hip_atomic_store(hbA + so, pk, __ATOMIC_RELAXED,
                                    __HIP_MEMORY_SCOPE_AGENT);    // fallback path (IF)
            out[(size_t)t * HID + unit] = h_out;
            if (t == T_STEPS - 1) {
                out[(size_t)T_STEPS * HID + unit]       = h_out;  // h_last
                out[(size_t)T_STEPS * HID + HID + unit] = c;      // c_last
            }
        }
        // NO producer drains (R2/R4: measured pure cost). Write-through L1 means the
        // sc0 stores reach the local L2 promptly on their own.
        // no trailing barrier: spin discipline prevents WG-internal LDS races (R3 proof)
    }

    if (w == 0 && tid == 0) {
        // release the anti-DVFS spinners, then re-arm the election protocol
        __hip_atomic_store(ctl + 10, DONE_MAGIC, __ATOMIC_RELEASE, __HIP_MEMORY_SCOPE_AGENT);
        __hip_atomic_store(ctl + 0, 0u, __ATOMIC_RELAXED, __HIP_MEMORY_SCOPE_AGENT);
    }
}

extern "C" void kernel_launch(void* const* d_in, const int* in_sizes, int n_in,
                              void* d_out, int out_size, void* d_ws, size_t ws_size,
                              hipStream_t stream) {
    const int*   tokens = (const int*)d_in[0];
    const float* emb    = (const float*)d_in[1];
    const float* Wih    = (const float*)d_in[2];
    const float* Whh    = (const float*)d_in[3];
    const float* bih    = (const float*)d_in[4];
    const float* bhh    = (const float*)d_in[5];
    float* out = (float*)d_out;
    unsigned long long* hbL = (unsigned long long*)d_ws;                    // [2][256] u64
    unsigned long long* hbA = (unsigned long long*)((char*)d_ws + 4096);    // [2][256] u64
    unsigned* ctl = (unsigned*)((char*)d_ws + 8192);                        // ready, elected, cnt[8], done

    lstm_scan<<<NBLK, THREADS, 0, stream>>>(tokens, emb, Wih, Whh, bih, bhh, out, hbL, hbA, ctl);
}